// Round 12
// baseline (1005.303 us; speedup 1.0000x reference)
//
#include <hip/hip_runtime.h>

#define TSTEPS 1024

typedef _Float16 half8  __attribute__((ext_vector_type(8)));
typedef _Float16 half4v __attribute__((ext_vector_type(4)));
typedef float    f32x4  __attribute__((ext_vector_type(4)));

#define MFMA16(A_, B_, C_) __builtin_amdgcn_mfma_f32_16x16x32_f16((A_), (B_), (C_), 0, 0, 0)

__device__ __forceinline__ float fast_rcp(float x) { return __builtin_amdgcn_rcpf(x); }
__device__ __forceinline__ float fast_exp2(float x) {
#if __has_builtin(__builtin_amdgcn_exp2f)
    return __builtin_amdgcn_exp2f(x);
#else
    return exp2f(x);
#endif
}

// load 8 consecutive fp32, scale, convert to packed f16 MFMA fragment
__device__ __forceinline__ half8 load_w8s(const float* p, float s) {
    const float4 a = ((const float4*)p)[0];
    const float4 b = ((const float4*)p)[1];
    half8 r;
    r[0] = (_Float16)(s * a.x); r[1] = (_Float16)(s * a.y);
    r[2] = (_Float16)(s * a.z); r[3] = (_Float16)(s * a.w);
    r[4] = (_Float16)(s * b.x); r[5] = (_Float16)(s * b.y);
    r[6] = (_Float16)(s * b.z); r[7] = (_Float16)(s * b.w);
    return r;
}

// ONE WAVE = ONE CHAIN. 1024 single-wave blocks (4/CU, one per SIMD, all
// 256 CUs busy -- vs 64 CUs in R7-R11). The whole 2-layer GRU for one
// batch chain runs inside one wave:
//  - h-state lives in tiny LDS buffers; B-fragments read from them are
//    BROADCAST (same address per quad-group), so all 16 MFMA columns
//    compute the same chain -- the redundancy is free (MFMA pipe ~97%
//    idle in R11) and buys zero cross-wave coupling.
//  - D (C-layout) is valid on every lane; lanes nl==0 write the 4-unit
//    f32x4 preact slices to LDS; after an intra-wave sync every lane L
//    picks up unit L -> 1 GRU1 triple/lane + 1 GRU2 triple on lanes<32.
//  - single-buffered s_h1/s_h2: within a wave, top-of-tick B-frag reads
//    precede bottom-of-tick h-writes in program order; __syncthreads in
//    a 1-wave block is just a waitcnt (no inter-SIMD barrier skew, and
//    the compiler can pipeline across ticks).
// GRU2 runs one step behind GRU1 (tick t: GRU1 step t, GRU2 step t-1),
// same lag scheme as R8; extra tick t=TSTEPS drains GRU2.
// Gate math in exp2 form, weights pre-scaled (r,z: -log2e; n: 2*log2e) --
// numerics identical to R10/R11 (absmax 2e-3).
// MFMA layouts (m89/m120-verified): A[m=lane&15][k=quad*8+j],
// B[k=quad*8+j][n=lane&15], C/D: col(n)=lane&15, row(m)=quad*4+reg.
__global__ __launch_bounds__(64, 1)
void gru2_encoder(const float* __restrict__ x,
                  const float* __restrict__ W_ih1,
                  const float* __restrict__ W_hh1,
                  const float* __restrict__ b_ih1,
                  const float* __restrict__ b_hh1,
                  const float* __restrict__ W_ih2,
                  const float* __restrict__ W_hh2,
                  const float* __restrict__ b_ih2,
                  const float* __restrict__ b_hh2,
                  float* __restrict__ out)
{
    const int chain = blockIdx.x;     // 1024 blocks = 1024 chains
    const int lane  = threadIdx.x;    // 64
    const int nl    = lane & 15;
    const int quad  = lane >> 4;

    const float SNEG = -1.44269504f;  // -log2(e)
    const float SP2  =  2.88539008f;  // 2*log2(e)

    __shared__ __align__(16) _Float16 s_x[TSTEPS];  // this chain's x, f16
    __shared__ __align__(16) _Float16 s_h1[64];     // h1 state (single buffer)
    __shared__ __align__(16) _Float16 s_h2[32];     // h2 state (single buffer)
    __shared__ __align__(16) float    preA[192];    // GRU1 preacts [gate*64+unit]
    __shared__ __align__(16) float    preB[128];    // GRU2 preacts [gate*32+unit] (r,z,nx,nh)

    // ---- stage x (coalesced float4 -> f16), zero h state
    {
        const float4* xp = (const float4*)(x + (size_t)chain * TSTEPS);
        #pragma unroll
        for (int q = 0; q < 4; ++q) {
            const float4 v = xp[q * 64 + lane];
            half4v h;
            h[0] = (_Float16)v.x; h[1] = (_Float16)v.y;
            h[2] = (_Float16)v.z; h[3] = (_Float16)v.w;
            *(half4v*)&s_x[4 * (q * 64 + lane)] = h;
        }
    }
    s_h1[lane] = (_Float16)0.0f;
    if (lane < 32) s_h2[lane] = (_Float16)0.0f;
    __syncthreads();

    // ---- GRU1 weight fragments: 4 unit-tiles x 3 gates x 2 K-chunks
    half8 Ar[4][2], Az[4][2], An[4][2];
    f32x4 Cr[4], Cz[4], Cn[4];
    #pragma unroll
    for (int g = 0; g < 4; ++g) {
        const int ur = g * 16 + nl;         // A-row unit
        const int u4 = g * 16 + quad * 4;   // this lane's 4 D-units
        Ar[g][0] = load_w8s(W_hh1 + (size_t)(ur)       * 64 + quad * 8,      SNEG);
        Ar[g][1] = load_w8s(W_hh1 + (size_t)(ur)       * 64 + 32 + quad * 8, SNEG);
        Az[g][0] = load_w8s(W_hh1 + (size_t)(64 + ur)  * 64 + quad * 8,      SNEG);
        Az[g][1] = load_w8s(W_hh1 + (size_t)(64 + ur)  * 64 + 32 + quad * 8, SNEG);
        An[g][0] = load_w8s(W_hh1 + (size_t)(128 + ur) * 64 + quad * 8,      SP2);
        An[g][1] = load_w8s(W_hh1 + (size_t)(128 + ur) * 64 + 32 + quad * 8, SP2);
        const float4 bir = *(const float4*)(b_ih1 + u4);
        const float4 bhr = *(const float4*)(b_hh1 + u4);
        const float4 biz = *(const float4*)(b_ih1 + 64 + u4);
        const float4 bhz = *(const float4*)(b_hh1 + 64 + u4);
        const float4 bhn = *(const float4*)(b_hh1 + 128 + u4);
        Cr[g] = f32x4{SNEG*(bir.x+bhr.x), SNEG*(bir.y+bhr.y), SNEG*(bir.z+bhr.z), SNEG*(bir.w+bhr.w)};
        Cz[g] = f32x4{SNEG*(biz.x+bhz.x), SNEG*(biz.y+bhz.y), SNEG*(biz.z+bhz.z), SNEG*(biz.w+bhz.w)};
        Cn[g] = f32x4{SP2*bhn.x, SP2*bhn.y, SP2*bhn.z, SP2*bhn.w};
    }
    // per-lane x-path scalars (lane L <-> GRU1 unit L)
    const float twr = SNEG * W_ih1[lane];
    const float twz = SNEG * W_ih1[64 + lane];
    const float twn = SP2  * W_ih1[128 + lane];
    const float tbn = SP2  * b_ih1[128 + lane];

    // ---- GRU2 weight fragments: 2 unit-tiles
    half8 Ir[2][2], Iz[2][2], In[2][2], Hr[2], Hz[2], Hn[2];
    f32x4 Gr[2], Gz[2], Gnx[2], Gnh[2];
    #pragma unroll
    for (int v = 0; v < 2; ++v) {
        const int vr = v * 16 + nl;
        const int v4 = v * 16 + quad * 4;
        Ir[v][0] = load_w8s(W_ih2 + (size_t)(vr)      * 64 + quad * 8,      SNEG);
        Ir[v][1] = load_w8s(W_ih2 + (size_t)(vr)      * 64 + 32 + quad * 8, SNEG);
        Iz[v][0] = load_w8s(W_ih2 + (size_t)(32 + vr) * 64 + quad * 8,      SNEG);
        Iz[v][1] = load_w8s(W_ih2 + (size_t)(32 + vr) * 64 + 32 + quad * 8, SNEG);
        In[v][0] = load_w8s(W_ih2 + (size_t)(64 + vr) * 64 + quad * 8,      SP2);
        In[v][1] = load_w8s(W_ih2 + (size_t)(64 + vr) * 64 + 32 + quad * 8, SP2);
        Hr[v]    = load_w8s(W_hh2 + (size_t)(vr)      * 32 + quad * 8,      SNEG);
        Hz[v]    = load_w8s(W_hh2 + (size_t)(32 + vr) * 32 + quad * 8,      SNEG);
        Hn[v]    = load_w8s(W_hh2 + (size_t)(64 + vr) * 32 + quad * 8,      SP2);
        const float4 bir = *(const float4*)(b_ih2 + v4);
        const float4 bhr = *(const float4*)(b_hh2 + v4);
        const float4 biz = *(const float4*)(b_ih2 + 32 + v4);
        const float4 bhz = *(const float4*)(b_hh2 + 32 + v4);
        const float4 bin = *(const float4*)(b_ih2 + 64 + v4);
        const float4 bhn = *(const float4*)(b_hh2 + 64 + v4);
        Gr[v]  = f32x4{SNEG*(bir.x+bhr.x), SNEG*(bir.y+bhr.y), SNEG*(bir.z+bhr.z), SNEG*(bir.w+bhr.w)};
        Gz[v]  = f32x4{SNEG*(biz.x+bhz.x), SNEG*(biz.y+bhz.y), SNEG*(biz.z+bhz.z), SNEG*(biz.w+bhz.w)};
        Gnx[v] = f32x4{SP2*bin.x, SP2*bin.y, SP2*bin.z, SP2*bin.w};
        Gnh[v] = f32x4{SP2*bhn.x, SP2*bhn.y, SP2*bhn.z, SP2*bhn.w};
    }

    float h1prev = 0.0f;    // h1[unit=lane]
    float h2prev = 0.0f;    // h2[unit=lane] (lane<32)

    for (int t = 0; t <= TSTEPS; ++t) {
        // top-of-tick state reads (h1(t-1), h2(t-2)) -- broadcast b128 per quad
        const half8 B0 = *(const half8*)&s_h1[quad * 8];        // k 0..31
        const half8 B1 = *(const half8*)&s_h1[32 + quad * 8];   // k 32..63
        const half8 Bh = *(const half8*)&s_h2[quad * 8];        // k 0..31 of h2

        if (t < TSTEPS) {
            // GRU1 step t: 24 MFMA, preacts -> preA (lanes nl==0)
            #pragma unroll
            for (int g = 0; g < 4; ++g) {
                f32x4 aR = MFMA16(Ar[g][0], B0, Cr[g]); aR = MFMA16(Ar[g][1], B1, aR);
                f32x4 aZ = MFMA16(Az[g][0], B0, Cz[g]); aZ = MFMA16(Az[g][1], B1, aZ);
                f32x4 aN = MFMA16(An[g][0], B0, Cn[g]); aN = MFMA16(An[g][1], B1, aN);
                if (nl == 0) {
                    *(f32x4*)&preA[g * 16 + quad * 4]        = aR;
                    *(f32x4*)&preA[64 + g * 16 + quad * 4]   = aZ;
                    *(f32x4*)&preA[128 + g * 16 + quad * 4]  = aN;
                }
            }
        }
        if (t >= 1) {
            // GRU2 step t-1: 18 MFMA over h1(t-1), h2(t-2); preacts -> preB
            #pragma unroll
            for (int v = 0; v < 2; ++v) {
                f32x4 aR  = MFMA16(Ir[v][0], B0, Gr[v]);  aR  = MFMA16(Ir[v][1], B1, aR);
                aR  = MFMA16(Hr[v], Bh, aR);
                f32x4 aZ  = MFMA16(Iz[v][0], B0, Gz[v]);  aZ  = MFMA16(Iz[v][1], B1, aZ);
                aZ  = MFMA16(Hz[v], Bh, aZ);
                f32x4 aNx = MFMA16(In[v][0], B0, Gnx[v]); aNx = MFMA16(In[v][1], B1, aNx);
                f32x4 aNh = MFMA16(Hn[v], Bh, Gnh[v]);
                if (nl == 0) {
                    *(f32x4*)&preB[v * 16 + quad * 4]        = aR;
                    *(f32x4*)&preB[32 + v * 16 + quad * 4]   = aZ;
                    *(f32x4*)&preB[64 + v * 16 + quad * 4]   = aNx;
                    *(f32x4*)&preB[96 + v * 16 + quad * 4]   = aNh;
                }
            }
        }
        __syncthreads();   // 1-wave block: compiles to a waitcnt, no barrier skew

        if (t < TSTEPS) {
            // GRU1 gate math: lane L owns unit L
            const float pR = preA[lane];
            const float pZ = preA[64 + lane];
            const float pN = preA[128 + lane];
            const float xv = (float)s_x[t];
            const float ea = fast_exp2(fmaf(twr, xv, pR));      // e^{-ar}
            const float eb = fast_exp2(fmaf(twz, xv, pZ));      // e^{-az}
            const float d1 = 1.0f + ea, d2 = 1.0f + eb;
            const float inv = fast_rcp(d1 * d2);
            const float r = d2 * inv, z = d1 * inv;
            const float nx = fmaf(twn, xv, tbn);
            const float ec = fast_exp2(fmaf(r, pN, nx));        // e^{2an}
            const float nn = fmaf(-2.0f, fast_rcp(ec + 1.0f), 1.0f);
            h1prev = nn + z * (h1prev - nn);
            s_h1[lane] = (_Float16)h1prev;                      // h1(t)
        }
        if (t >= 1 && lane < 32) {
            // GRU2 gate math: lane L owns unit L
            const float pR  = preB[lane];
            const float pZ  = preB[32 + lane];
            const float pNx = preB[64 + lane];
            const float pNh = preB[96 + lane];
            const float ea = fast_exp2(pR);
            const float eb = fast_exp2(pZ);
            const float d1 = 1.0f + ea, d2 = 1.0f + eb;
            const float inv = fast_rcp(d1 * d2);
            const float r2 = d2 * inv, z2 = d1 * inv;
            const float ec = fast_exp2(fmaf(r2, pNh, pNx));
            const float n2 = fmaf(-2.0f, fast_rcp(ec + 1.0f), 1.0f);
            h2prev = n2 + z2 * (h2prev - n2);
            s_h2[lane] = (_Float16)h2prev;                      // h2(t-1)
        }
        __syncthreads();   // orders h-writes before next tick's B-frag reads
    }

    if (lane < 32) out[(size_t)chain * 32 + lane] = h2prev;
}

extern "C" void kernel_launch(void* const* d_in, const int* in_sizes, int n_in,
                              void* d_out, int out_size, void* d_ws, size_t ws_size,
                              hipStream_t stream) {
    const float* x     = (const float*)d_in[0];
    const float* W_ih1 = (const float*)d_in[1];
    const float* W_hh1 = (const float*)d_in[2];
    const float* b_ih1 = (const float*)d_in[3];
    const float* b_hh1 = (const float*)d_in[4];
    const float* W_ih2 = (const float*)d_in[5];
    const float* W_hh2 = (const float*)d_in[6];
    const float* b_ih2 = (const float*)d_in[7];
    const float* b_hh2 = (const float*)d_in[8];
    float* out = (float*)d_out;

    gru2_encoder<<<dim3(1024), dim3(64), 0, stream>>>(
        x, W_ih1, W_hh1, b_ih1, b_hh1, W_ih2, W_hh2, b_ih2, b_hh2, out);
}

// Round 13
// 556.107 us; speedup vs baseline: 1.8078x; 1.8078x over previous
//
#include <hip/hip_runtime.h>

#define TSTEPS 1024
#define CH 4               // chains per block (cols 0..3 of the MFMA tile)

typedef _Float16 half8  __attribute__((ext_vector_type(8)));
typedef _Float16 half4v __attribute__((ext_vector_type(4)));
typedef float    f32x4  __attribute__((ext_vector_type(4)));

#define MFMA16(A_, B_, C_) __builtin_amdgcn_mfma_f32_16x16x32_f16((A_), (B_), (C_), 0, 0, 0)

__device__ __forceinline__ float fast_rcp(float x) { return __builtin_amdgcn_rcpf(x); }
__device__ __forceinline__ float fast_exp2(float x) {
#if __has_builtin(__builtin_amdgcn_exp2f)
    return __builtin_amdgcn_exp2f(x);
#else
    return exp2f(x);
#endif
}

// load 8 consecutive fp32, scale, convert to packed f16 MFMA fragment
__device__ __forceinline__ half8 load_w8s(const float* p, float s) {
    const float4 a = ((const float4*)p)[0];
    const float4 b = ((const float4*)p)[1];
    half8 r;
    r[0] = (_Float16)(s * a.x); r[1] = (_Float16)(s * a.y);
    r[2] = (_Float16)(s * a.z); r[3] = (_Float16)(s * a.w);
    r[4] = (_Float16)(s * b.x); r[5] = (_Float16)(s * b.y);
    r[6] = (_Float16)(s * b.z); r[7] = (_Float16)(s * b.w);
    return r;
}

// R8 structure scaled out to ALL 256 CUs: 256 blocks x 4 chains (was 64x16).
// Issue accounting (R12 post-mortem): per chain-tick needs ~270 SIMD-cyc
// (trans 120 + MFMA 51 + VALU/LDS ~100); R8 packed 4 chains/SIMD (64 CUs)
// -> ~1080 cyc/tick issue-bound. Same structure at 1 chain/SIMD -> ~550
// cyc busiest SIMD + ~300 overhead. MFMA cols 4..15 are wasted redundancy
// -- free, the matrix pipe was ~97% idle per wave.
//   waves 0..3: GRU1 unit-tile wid: 6 MFMA + 1 triple/lane.
//   waves 4..5: GRU2 unit-tile, ONE STEP BEHIND: 9 MFMA + 1 triple/lane.
// One __syncthreads per tick. exp2 pre-scaled gate math (R10-validated).
// MFMA layouts (m89/m120-verified): A[m=lane&15][k=quad*8+j],
// B[k=quad*8+j][n=lane&15], C/D: col(n)=lane&15, row(m)=quad*4+reg.
// h-parity (R8 scheme): at tick t, h1(t-1) in s_h1[(t+1)&1]; GRU2 reads
// h2(t-2) from s_h2[t&1], writes h2(t-1) to s_h2[(t+1)&1].
// LDS cols 4..15 stay zero (staged once); publishes to them are harmless
// garbage that is never read as output and feeds only dead MFMA columns.
__global__ __launch_bounds__(384, 1)
void gru2_encoder(const float* __restrict__ x,
                  const float* __restrict__ W_ih1,
                  const float* __restrict__ W_hh1,
                  const float* __restrict__ b_ih1,
                  const float* __restrict__ b_hh1,
                  const float* __restrict__ W_ih2,
                  const float* __restrict__ W_hh2,
                  const float* __restrict__ b_ih2,
                  const float* __restrict__ b_hh2,
                  float* __restrict__ out)
{
    const int blk  = blockIdx.x;    // 256 blocks, CH chains each
    const int tid  = threadIdx.x;   // 384
    const int lane = tid & 63;
    const int wid  = tid >> 6;      // 0..5
    const int nl   = lane & 15;     // chain col (0..CH-1 real, rest dead)
    const int quad = lane >> 4;     // 0..3
    const int chain0 = blk * CH;

    const float SNEG = -1.44269504f;       // -log2(e)
    const float SP2  =  2.88539008f;       // 2*log2(e)

    __shared__ __align__(16) _Float16 s_h1[2][16][72];   // [par][chain][unit64+pad]
    __shared__ __align__(16) _Float16 s_h2[2][16][40];   // [par][chain][unit32+pad]
    __shared__ __align__(16) _Float16 s_x[TSTEPS][16];   // x f16, [t][chain] (cols>=CH zero)

    // ---- one-time staging: x cols 0..CH-1 from HBM, cols CH..15 zero
    for (int idx = tid; idx < 16 * TSTEPS; idx += 384) {
        const int m = idx >> 10, t = idx & (TSTEPS - 1);
        s_x[t][m] = (m < CH) ? (_Float16)x[(size_t)(chain0 + m) * TSTEPS + t]
                             : (_Float16)0.0f;
    }
    {
        _Float16* p1 = &s_h1[0][0][0];
        for (int idx = tid; idx < 2 * 16 * 72; idx += 384) p1[idx] = (_Float16)0.0f;
        _Float16* p2 = &s_h2[0][0][0];
        for (int idx = tid; idx < 2 * 16 * 40; idx += 384) p2[idx] = (_Float16)0.0f;
    }
    __syncthreads();

    if (wid < 4) {
        // ================= GRU1, unit-tile wid =================
        const int U0 = wid * 16;
        const int ur = U0 + nl;
        const int u4 = U0 + quad * 4;
        const half8 aWr0 = load_w8s(W_hh1 + (size_t)(ur)       * 64 + quad * 8,      SNEG);
        const half8 aWr1 = load_w8s(W_hh1 + (size_t)(ur)       * 64 + 32 + quad * 8, SNEG);
        const half8 aWz0 = load_w8s(W_hh1 + (size_t)(64 + ur)  * 64 + quad * 8,      SNEG);
        const half8 aWz1 = load_w8s(W_hh1 + (size_t)(64 + ur)  * 64 + 32 + quad * 8, SNEG);
        const half8 aWn0 = load_w8s(W_hh1 + (size_t)(128 + ur) * 64 + quad * 8,      SP2);
        const half8 aWn1 = load_w8s(W_hh1 + (size_t)(128 + ur) * 64 + 32 + quad * 8, SP2);
        const float4 bir = *(const float4*)(b_ih1 + u4);
        const float4 bhr = *(const float4*)(b_hh1 + u4);
        const float4 biz = *(const float4*)(b_ih1 + 64 + u4);
        const float4 bhz = *(const float4*)(b_hh1 + 64 + u4);
        const float4 bin = *(const float4*)(b_ih1 + 128 + u4);
        const float4 bhn = *(const float4*)(b_hh1 + 128 + u4);
        const f32x4 Cr = {SNEG*(bir.x+bhr.x), SNEG*(bir.y+bhr.y), SNEG*(bir.z+bhr.z), SNEG*(bir.w+bhr.w)};
        const f32x4 Cz = {SNEG*(biz.x+bhz.x), SNEG*(biz.y+bhz.y), SNEG*(biz.z+bhz.z), SNEG*(biz.w+bhz.w)};
        const f32x4 Cn = {SP2*bhn.x, SP2*bhn.y, SP2*bhn.z, SP2*bhn.w};
        const float4 wr = *(const float4*)(W_ih1 + u4);
        const float4 wz = *(const float4*)(W_ih1 + 64 + u4);
        const float4 wn = *(const float4*)(W_ih1 + 128 + u4);
        const float twr[4] = {SNEG*wr.x, SNEG*wr.y, SNEG*wr.z, SNEG*wr.w};
        const float twz[4] = {SNEG*wz.x, SNEG*wz.y, SNEG*wz.z, SNEG*wz.w};
        const float twn[4] = {SP2*wn.x,  SP2*wn.y,  SP2*wn.z,  SP2*wn.w};
        const float tbn[4] = {SP2*bin.x, SP2*bin.y, SP2*bin.z, SP2*bin.w};

        float h1s[4] = {};
        for (int t = 0; t <= TSTEPS; ++t) {
            if (t < TSTEPS) {
                const int pr = (t + 1) & 1;
                const half8 B0 = *(const half8*)&s_h1[pr][nl][quad * 8];
                const half8 B1 = *(const half8*)&s_h1[pr][nl][32 + quad * 8];
                f32x4 aR = MFMA16(aWr0, B0, Cr); aR = MFMA16(aWr1, B1, aR);
                f32x4 aZ = MFMA16(aWz0, B0, Cz); aZ = MFMA16(aWz1, B1, aZ);
                f32x4 aN = MFMA16(aWn0, B0, Cn); aN = MFMA16(aWn1, B1, aN);
                const float xv = (float)s_x[t][nl];
                half4v hv;
                #pragma unroll
                for (int i = 0; i < 4; ++i) {
                    const float ea = fast_exp2(fmaf(twr[i], xv, aR[i]));   // e^{-ar}
                    const float eb = fast_exp2(fmaf(twz[i], xv, aZ[i]));   // e^{-az}
                    const float d1 = 1.0f + ea, d2 = 1.0f + eb;
                    const float inv = fast_rcp(d1 * d2);
                    const float r = d2 * inv, z = d1 * inv;
                    const float nx = fmaf(twn[i], xv, tbn[i]);
                    const float ec = fast_exp2(fmaf(r, aN[i], nx));        // e^{2an}
                    const float nn = fmaf(-2.0f, fast_rcp(ec + 1.0f), 1.0f);
                    h1s[i] = nn + z * (h1s[i] - nn);
                    hv[i] = (_Float16)h1s[i];
                }
                *(half4v*)&s_h1[t & 1][nl][u4] = hv;   // one contiguous b64
            }
            __syncthreads();
        }
    } else {
        // ================= GRU2, unit-tile (wid-4), one step behind =================
        const int V0 = (wid - 4) * 16;
        const int vr = V0 + nl;
        const int v4 = V0 + quad * 4;
        const half8 AiR0 = load_w8s(W_ih2 + (size_t)(vr)      * 64 + quad * 8,      SNEG);
        const half8 AiR1 = load_w8s(W_ih2 + (size_t)(vr)      * 64 + 32 + quad * 8, SNEG);
        const half8 AiZ0 = load_w8s(W_ih2 + (size_t)(32 + vr) * 64 + quad * 8,      SNEG);
        const half8 AiZ1 = load_w8s(W_ih2 + (size_t)(32 + vr) * 64 + 32 + quad * 8, SNEG);
        const half8 AiN0 = load_w8s(W_ih2 + (size_t)(64 + vr) * 64 + quad * 8,      SP2);
        const half8 AiN1 = load_w8s(W_ih2 + (size_t)(64 + vr) * 64 + 32 + quad * 8, SP2);
        const half8 AhR = load_w8s(W_hh2 + (size_t)(vr)      * 32 + quad * 8,      SNEG);
        const half8 AhZ = load_w8s(W_hh2 + (size_t)(32 + vr) * 32 + quad * 8,      SNEG);
        const half8 AhN = load_w8s(W_hh2 + (size_t)(64 + vr) * 32 + quad * 8,      SP2);
        const float4 bir = *(const float4*)(b_ih2 + v4);
        const float4 bhr = *(const float4*)(b_hh2 + v4);
        const float4 biz = *(const float4*)(b_ih2 + 32 + v4);
        const float4 bhz = *(const float4*)(b_hh2 + 32 + v4);
        const float4 bin = *(const float4*)(b_ih2 + 64 + v4);
        const float4 bhn = *(const float4*)(b_hh2 + 64 + v4);
        const f32x4 Gr  = {SNEG*(bir.x+bhr.x), SNEG*(bir.y+bhr.y), SNEG*(bir.z+bhr.z), SNEG*(bir.w+bhr.w)};
        const f32x4 Gz  = {SNEG*(biz.x+bhz.x), SNEG*(biz.y+bhz.y), SNEG*(biz.z+bhz.z), SNEG*(biz.w+bhz.w)};
        const f32x4 Gnx = {SP2*bin.x, SP2*bin.y, SP2*bin.z, SP2*bin.w};
        const f32x4 Gnh = {SP2*bhn.x, SP2*bhn.y, SP2*bhn.z, SP2*bhn.w};

        float h2s[4] = {};
        for (int t = 0; t <= TSTEPS; ++t) {
            if (t >= 1) {
                const int pA = (t + 1) & 1;            // parity of h1(t-1)
                const half8 B0 = *(const half8*)&s_h1[pA][nl][quad * 8];
                const half8 B1 = *(const half8*)&s_h1[pA][nl][32 + quad * 8];
                const half8 Bh = *(const half8*)&s_h2[t & 1][nl][quad * 8];   // h2(t-2)
                f32x4 aR = MFMA16(AiR0, B0, Gr);  aR = MFMA16(AiR1, B1, aR);
                aR = MFMA16(AhR, Bh, aR);
                f32x4 aZ = MFMA16(AiZ0, B0, Gz);  aZ = MFMA16(AiZ1, B1, aZ);
                aZ = MFMA16(AhZ, Bh, aZ);
                f32x4 aNx = MFMA16(AiN0, B0, Gnx); aNx = MFMA16(AiN1, B1, aNx);
                f32x4 aNh = MFMA16(AhN, Bh, Gnh);
                half4v hv;
                #pragma unroll
                for (int i = 0; i < 4; ++i) {
                    const float ea = fast_exp2(aR[i]);
                    const float eb = fast_exp2(aZ[i]);
                    const float d1 = 1.0f + ea, d2 = 1.0f + eb;
                    const float inv = fast_rcp(d1 * d2);
                    const float r2 = d2 * inv, z2 = d1 * inv;
                    const float ec = fast_exp2(fmaf(r2, aNh[i], aNx[i]));
                    const float n2 = fmaf(-2.0f, fast_rcp(ec + 1.0f), 1.0f);
                    h2s[i] = n2 + z2 * (h2s[i] - n2);
                    hv[i] = (_Float16)h2s[i];
                }
                *(half4v*)&s_h2[(t + 1) & 1][nl][v4] = hv;   // h2(t-1), one b64
            }
            __syncthreads();
        }

        if (nl < CH) {
            float4 o = {h2s[0], h2s[1], h2s[2], h2s[3]};
            *(float4*)(out + (size_t)(chain0 + nl) * 32 + v4) = o;   // one dwordx4
        }
    }
}

extern "C" void kernel_launch(void* const* d_in, const int* in_sizes, int n_in,
                              void* d_out, int out_size, void* d_ws, size_t ws_size,
                              hipStream_t stream) {
    const float* x     = (const float*)d_in[0];
    const float* W_ih1 = (const float*)d_in[1];
    const float* W_hh1 = (const float*)d_in[2];
    const float* b_ih1 = (const float*)d_in[3];
    const float* b_hh1 = (const float*)d_in[4];
    const float* W_ih2 = (const float*)d_in[5];
    const float* W_hh2 = (const float*)d_in[6];
    const float* b_ih2 = (const float*)d_in[7];
    const float* b_hh2 = (const float*)d_in[8];
    float* out = (float*)d_out;

    gru2_encoder<<<dim3(1024 / CH), dim3(384), 0, stream>>>(
        x, W_ih1, W_hh1, b_ih1, b_hh1, W_ih2, W_hh2, b_ih2, b_hh2, out);
}

// Round 14
// 472.017 us; speedup vs baseline: 2.1298x; 1.1781x over previous
//
#include <hip/hip_runtime.h>

#define TSTEPS 1024
#define CH 4               // chains per block (cols 0..3 of the MFMA tile)

typedef _Float16 half8  __attribute__((ext_vector_type(8)));
typedef _Float16 half4v __attribute__((ext_vector_type(4)));
typedef float    f32x4  __attribute__((ext_vector_type(4)));

#define MFMA16(A_, B_, C_) __builtin_amdgcn_mfma_f32_16x16x32_f16((A_), (B_), (C_), 0, 0, 0)

__device__ __forceinline__ float fast_rcp(float x) { return __builtin_amdgcn_rcpf(x); }
__device__ __forceinline__ float fast_exp2(float x) {
#if __has_builtin(__builtin_amdgcn_exp2f)
    return __builtin_amdgcn_exp2f(x);
#else
    return exp2f(x);
#endif
}

// load 8 consecutive fp32, scale, convert to packed f16 MFMA fragment
__device__ __forceinline__ half8 load_w8s(const float* p, float s) {
    const float4 a = ((const float4*)p)[0];
    const float4 b = ((const float4*)p)[1];
    half8 r;
    r[0] = (_Float16)(s * a.x); r[1] = (_Float16)(s * a.y);
    r[2] = (_Float16)(s * a.z); r[3] = (_Float16)(s * a.w);
    r[4] = (_Float16)(s * b.x); r[5] = (_Float16)(s * b.y);
    r[6] = (_Float16)(s * b.z); r[7] = (_Float16)(s * b.w);
    return r;
}

// R13 + INTRA-WAVE preact redistribution. R13 post-mortem: tick_time
// (~1300cyc) is set by the busiest SIMD (GRU1 wave + GRU2 wave co-resident),
// whose largest issue term is quarter-rate transcendentals: 4 gate-triples
// per lane (~224cyc/wave). Fix: after MFMA, lanes nl<CH write the f32x4
// preacts to a per-wave LDS scratch (b128, no cross-wave sync -- same-wave
// write->read is ordered by lgkmcnt), then ALL 64 lanes read back one
// (unit,chain) pair -> 1 triple/lane. Saves ~170 issue-cyc on every heavy
// wave; the added LDS round-trip latency is hidden by the co-resident wave
// (R8 vs R11: 2 waves/SIMD hide each other's stalls).
//   waves 0..3: GRU1 unit-tile wid: 6 MFMA + 1 triple/lane.
//   waves 4..5: GRU2 unit-tile, ONE STEP BEHIND: 9 MFMA + 1 triple/lane.
// One __syncthreads per tick. exp2 pre-scaled gate math (R10-validated).
// MFMA layouts (m89/m120-verified): A[m=lane&15][k=quad*8+j],
// B[k=quad*8+j][n=lane&15], C/D: col(n)=lane&15, row(m)=quad*4+reg.
// h-parity (R8 scheme): at tick t, h1(t-1) in s_h1[(t+1)&1]; GRU2 reads
// h2(t-2) from s_h2[t&1], writes h2(t-1) to s_h2[(t+1)&1].
// h-state cols CH..15 stay zero forever (init once, never rewritten):
// dead MFMA columns compute zeros.
__global__ __launch_bounds__(384, 1)
void gru2_encoder(const float* __restrict__ x,
                  const float* __restrict__ W_ih1,
                  const float* __restrict__ W_hh1,
                  const float* __restrict__ b_ih1,
                  const float* __restrict__ b_hh1,
                  const float* __restrict__ W_ih2,
                  const float* __restrict__ W_hh2,
                  const float* __restrict__ b_ih2,
                  const float* __restrict__ b_hh2,
                  float* __restrict__ out)
{
    const int blk  = blockIdx.x;    // 256 blocks, CH chains each
    const int tid  = threadIdx.x;   // 384
    const int lane = tid & 63;
    const int wid  = tid >> 6;      // 0..5
    const int nl   = lane & 15;     // chain col (0..CH-1 real, rest dead)
    const int quad = lane >> 4;     // 0..3
    const int uu   = lane >> 2;     // redistributed unit-within-tile (0..15)
    const int cc   = lane & 3;      // redistributed chain (0..3)
    const int chain0 = blk * CH;

    const float SNEG = -1.44269504f;       // -log2(e)
    const float SP2  =  2.88539008f;       // 2*log2(e)

    __shared__ __align__(16) _Float16 s_h1[2][16][72];   // [par][chain][unit64+pad]
    __shared__ __align__(16) _Float16 s_h2[2][16][40];   // [par][chain][unit32+pad]
    __shared__ __align__(16) _Float16 s_x[TSTEPS][16];   // x f16, [t][chain] (cols>=CH zero)
    // per-wave preact scratch: [gate][col(CH)][unit16+pad4] f32, stride 20 keeps b128 alignment
    __shared__ __align__(16) float sc1[4][3][CH][20];    // GRU1 waves 0..3
    __shared__ __align__(16) float sc2[2][4][CH][20];    // GRU2 waves 4..5 (r,z,nx,nh)

    // ---- one-time staging: x cols 0..CH-1 from HBM, cols CH..15 zero
    for (int idx = tid; idx < 16 * TSTEPS; idx += 384) {
        const int m = idx >> 10, t = idx & (TSTEPS - 1);
        s_x[t][m] = (m < CH) ? (_Float16)x[(size_t)(chain0 + m) * TSTEPS + t]
                             : (_Float16)0.0f;
    }
    {
        _Float16* p1 = &s_h1[0][0][0];
        for (int idx = tid; idx < 2 * 16 * 72; idx += 384) p1[idx] = (_Float16)0.0f;
        _Float16* p2 = &s_h2[0][0][0];
        for (int idx = tid; idx < 2 * 16 * 40; idx += 384) p2[idx] = (_Float16)0.0f;
    }
    __syncthreads();

    if (wid < 4) {
        // ================= GRU1, unit-tile wid =================
        const int U0 = wid * 16;
        const int ur = U0 + nl;
        const half8 aWr0 = load_w8s(W_hh1 + (size_t)(ur)       * 64 + quad * 8,      SNEG);
        const half8 aWr1 = load_w8s(W_hh1 + (size_t)(ur)       * 64 + 32 + quad * 8, SNEG);
        const half8 aWz0 = load_w8s(W_hh1 + (size_t)(64 + ur)  * 64 + quad * 8,      SNEG);
        const half8 aWz1 = load_w8s(W_hh1 + (size_t)(64 + ur)  * 64 + 32 + quad * 8, SNEG);
        const half8 aWn0 = load_w8s(W_hh1 + (size_t)(128 + ur) * 64 + quad * 8,      SP2);
        const half8 aWn1 = load_w8s(W_hh1 + (size_t)(128 + ur) * 64 + 32 + quad * 8, SP2);
        // biases in MFMA C operand (per MFMA-layout lane: 4 units u4..u4+3)
        const int u4 = U0 + quad * 4;
        const float4 bir = *(const float4*)(b_ih1 + u4);
        const float4 bhr = *(const float4*)(b_hh1 + u4);
        const float4 biz = *(const float4*)(b_ih1 + 64 + u4);
        const float4 bhz = *(const float4*)(b_hh1 + 64 + u4);
        const float4 bhn = *(const float4*)(b_hh1 + 128 + u4);
        const f32x4 Cr = {SNEG*(bir.x+bhr.x), SNEG*(bir.y+bhr.y), SNEG*(bir.z+bhr.z), SNEG*(bir.w+bhr.w)};
        const f32x4 Cz = {SNEG*(biz.x+bhz.x), SNEG*(biz.y+bhz.y), SNEG*(biz.z+bhz.z), SNEG*(biz.w+bhz.w)};
        const f32x4 Cn = {SP2*bhn.x, SP2*bhn.y, SP2*bhn.z, SP2*bhn.w};
        // x-path scalars for this lane's ONE redistributed unit (U0+uu)
        const int ru = U0 + uu;
        const float twr = SNEG * W_ih1[ru];
        const float twz = SNEG * W_ih1[64 + ru];
        const float twn = SP2  * W_ih1[128 + ru];
        const float tbn = SP2  * b_ih1[128 + ru];

        float h1s = 0.0f;   // h1[unit U0+uu][chain cc]
        for (int t = 0; t <= TSTEPS; ++t) {
            if (t < TSTEPS) {
                const int pr = (t + 1) & 1;
                const half8 B0 = *(const half8*)&s_h1[pr][nl][quad * 8];
                const half8 B1 = *(const half8*)&s_h1[pr][nl][32 + quad * 8];
                f32x4 aR = MFMA16(aWr0, B0, Cr); aR = MFMA16(aWr1, B1, aR);
                f32x4 aZ = MFMA16(aWz0, B0, Cz); aZ = MFMA16(aWz1, B1, aZ);
                f32x4 aN = MFMA16(aWn0, B0, Cn); aN = MFMA16(aWn1, B1, aN);
                // intra-wave redistribution: cols 0..CH-1 publish f32x4 (units quad*4..+3)
                if (nl < CH) {
                    *(f32x4*)&sc1[wid][0][nl][quad * 4] = aR;
                    *(f32x4*)&sc1[wid][1][nl][quad * 4] = aZ;
                    *(f32x4*)&sc1[wid][2][nl][quad * 4] = aN;
                }
                // same-wave LDS write->read: compiler inserts lgkmcnt wait
                const float pR = sc1[wid][0][cc][uu];
                const float pZ = sc1[wid][1][cc][uu];
                const float pN = sc1[wid][2][cc][uu];
                const float xv = (float)s_x[t][cc];
                const float ea = fast_exp2(fmaf(twr, xv, pR));     // e^{-ar}
                const float eb = fast_exp2(fmaf(twz, xv, pZ));     // e^{-az}
                const float d1 = 1.0f + ea, d2 = 1.0f + eb;
                const float inv = fast_rcp(d1 * d2);
                const float r = d2 * inv, z = d1 * inv;
                const float nx = fmaf(twn, xv, tbn);
                const float ec = fast_exp2(fmaf(r, pN, nx));       // e^{2an}
                const float nn = fmaf(-2.0f, fast_rcp(ec + 1.0f), 1.0f);
                h1s = nn + z * (h1s - nn);
                s_h1[t & 1][cc][ru] = (_Float16)h1s;               // b16, cols>=CH untouched (stay 0)
            }
            __syncthreads();
        }
    } else {
        // ================= GRU2, unit-tile (wid-4), one step behind =================
        const int w2 = wid - 4;
        const int V0 = w2 * 16;
        const int vr = V0 + nl;
        const half8 AiR0 = load_w8s(W_ih2 + (size_t)(vr)      * 64 + quad * 8,      SNEG);
        const half8 AiR1 = load_w8s(W_ih2 + (size_t)(vr)      * 64 + 32 + quad * 8, SNEG);
        const half8 AiZ0 = load_w8s(W_ih2 + (size_t)(32 + vr) * 64 + quad * 8,      SNEG);
        const half8 AiZ1 = load_w8s(W_ih2 + (size_t)(32 + vr) * 64 + 32 + quad * 8, SNEG);
        const half8 AiN0 = load_w8s(W_ih2 + (size_t)(64 + vr) * 64 + quad * 8,      SP2);
        const half8 AiN1 = load_w8s(W_ih2 + (size_t)(64 + vr) * 64 + 32 + quad * 8, SP2);
        const half8 AhR = load_w8s(W_hh2 + (size_t)(vr)      * 32 + quad * 8,      SNEG);
        const half8 AhZ = load_w8s(W_hh2 + (size_t)(32 + vr) * 32 + quad * 8,      SNEG);
        const half8 AhN = load_w8s(W_hh2 + (size_t)(64 + vr) * 32 + quad * 8,      SP2);
        const int v4 = V0 + quad * 4;
        const float4 bir = *(const float4*)(b_ih2 + v4);
        const float4 bhr = *(const float4*)(b_hh2 + v4);
        const float4 biz = *(const float4*)(b_ih2 + 32 + v4);
        const float4 bhz = *(const float4*)(b_hh2 + 32 + v4);
        const float4 bin = *(const float4*)(b_ih2 + 64 + v4);
        const float4 bhn = *(const float4*)(b_hh2 + 64 + v4);
        const f32x4 Gr  = {SNEG*(bir.x+bhr.x), SNEG*(bir.y+bhr.y), SNEG*(bir.z+bhr.z), SNEG*(bir.w+bhr.w)};
        const f32x4 Gz  = {SNEG*(biz.x+bhz.x), SNEG*(biz.y+bhz.y), SNEG*(biz.z+bhz.z), SNEG*(biz.w+bhz.w)};
        const f32x4 Gnx = {SP2*bin.x, SP2*bin.y, SP2*bin.z, SP2*bin.w};
        const f32x4 Gnh = {SP2*bhn.x, SP2*bhn.y, SP2*bhn.z, SP2*bhn.w};

        float h2s = 0.0f;   // h2[unit V0+uu][chain cc]
        for (int t = 0; t <= TSTEPS; ++t) {
            if (t >= 1) {
                const int pA = (t + 1) & 1;            // parity of h1(t-1)
                const half8 B0 = *(const half8*)&s_h1[pA][nl][quad * 8];
                const half8 B1 = *(const half8*)&s_h1[pA][nl][32 + quad * 8];
                const half8 Bh = *(const half8*)&s_h2[t & 1][nl][quad * 8];   // h2(t-2)
                f32x4 aR = MFMA16(AiR0, B0, Gr);  aR = MFMA16(AiR1, B1, aR);
                aR = MFMA16(AhR, Bh, aR);
                f32x4 aZ = MFMA16(AiZ0, B0, Gz);  aZ = MFMA16(AiZ1, B1, aZ);
                aZ = MFMA16(AhZ, Bh, aZ);
                f32x4 aNx = MFMA16(AiN0, B0, Gnx); aNx = MFMA16(AiN1, B1, aNx);
                f32x4 aNh = MFMA16(AhN, Bh, Gnh);
                if (nl < CH) {
                    *(f32x4*)&sc2[w2][0][nl][quad * 4] = aR;
                    *(f32x4*)&sc2[w2][1][nl][quad * 4] = aZ;
                    *(f32x4*)&sc2[w2][2][nl][quad * 4] = aNx;
                    *(f32x4*)&sc2[w2][3][nl][quad * 4] = aNh;
                }
                const float pR  = sc2[w2][0][cc][uu];
                const float pZ  = sc2[w2][1][cc][uu];
                const float pNx = sc2[w2][2][cc][uu];
                const float pNh = sc2[w2][3][cc][uu];
                const float ea = fast_exp2(pR);
                const float eb = fast_exp2(pZ);
                const float d1 = 1.0f + ea, d2 = 1.0f + eb;
                const float inv = fast_rcp(d1 * d2);
                const float r2 = d2 * inv, z2 = d1 * inv;
                const float ec = fast_exp2(fmaf(r2, pNh, pNx));
                const float n2 = fmaf(-2.0f, fast_rcp(ec + 1.0f), 1.0f);
                h2s = n2 + z2 * (h2s - n2);
                s_h2[(t + 1) & 1][cc][V0 + uu] = (_Float16)h2s;   // h2(t-1)
            }
            __syncthreads();
        }

        // lane holds h2 for (unit V0+uu, chain cc): coalesced-ish b32 stores
        out[(size_t)(chain0 + cc) * 32 + V0 + uu] = h2s;
    }
}

extern "C" void kernel_launch(void* const* d_in, const int* in_sizes, int n_in,
                              void* d_out, int out_size, void* d_ws, size_t ws_size,
                              hipStream_t stream) {
    const float* x     = (const float*)d_in[0];
    const float* W_ih1 = (const float*)d_in[1];
    const float* W_hh1 = (const float*)d_in[2];
    const float* b_ih1 = (const float*)d_in[3];
    const float* b_hh1 = (const float*)d_in[4];
    const float* W_ih2 = (const float*)d_in[5];
    const float* W_hh2 = (const float*)d_in[6];
    const float* b_ih2 = (const float*)d_in[7];
    const float* b_hh2 = (const float*)d_in[8];
    float* out = (float*)d_out;

    gru2_encoder<<<dim3(1024 / CH), dim3(384), 0, stream>>>(
        x, W_ih1, W_hh1, b_ih1, b_hh1, W_ih2, W_hh2, b_ih2, b_hh2, out);
}